// Round 3
// baseline (736.684 us; speedup 1.0000x reference)
//
#include <hip/hip_runtime.h>
#include <hip/hip_bf16.h>

#define NUM_STEPS 10
#define DT 0.1f

typedef __bf16 bf16_t;
typedef __bf16 bf16x8 __attribute__((ext_vector_type(8)));
typedef __bf16 bf16x4 __attribute__((ext_vector_type(4)));
typedef float f32x4 __attribute__((ext_vector_type(4)));

// async global->LDS, 16B per lane; LDS dst is wave-uniform base + lane*16
__device__ __forceinline__ void async16(const bf16_t* g, bf16_t* l) {
  __builtin_amdgcn_global_load_lds(
      (const __attribute__((address_space(1))) void*)g,
      (__attribute__((address_space(3))) void*)l, 16, 0, 0);
}

__global__ void cvt_f32_to_bf16(const float* __restrict__ in,
                                bf16_t* __restrict__ out, int n4) {
  int i = blockIdx.x * blockDim.x + threadIdx.x;
  if (i < n4) {
    float4 v = ((const float4*)in)[i];
    bf16x4 o = {(bf16_t)v.x, (bf16_t)v.y, (bf16_t)v.z, (bf16_t)v.w};
    ((bf16x4*)out)[i] = o;
  }
}

// one-shot: decay[h] = exp(-dt/tau[h])
__global__ void make_decay(const float* __restrict__ tau,
                           float* __restrict__ decay, int n) {
  int i = blockIdx.x * blockDim.x + threadIdx.x;
  if (i < n) decay[i] = __expf(-DT / tau[i]);
}

// C[M,N] = A[M,K] * B[N,K]^T   (NT, both row-major, K contiguous)
// Round 3: same geometry as round 2 (BM=256 BN=128 BK=64, 8 waves 4Mx2N,
// per-wave 64x64, verified addressing/epilogue) but the K-loop is rebuilt as
// a fine-grained PHASE schedule (T3+T4): each K-tile = 2 phases (one per
// 32-wide k-slice). Phase = { issue 3 global_load_lds for a half-tile 3
// half-tiles ahead; 8 ds_read_b128; setprio(1) 16 MFMA setprio(0);
// s_waitcnt vmcnt(6); s_barrier }. Loads are issued evenly (3 per ~600cyc
// instead of a 6-burst per tile) and never drained below vmcnt(3) until the
// tail -- the round-2 structure sustained only ~10 B/cyc/CU load return;
// this schedule is the m201/m218 regime (~18.5 B/cyc/CU).
// LDS: 2 tile-buffers x 48 KB (A 16 groups x 1024 el, B 8 x 1024 at +16384).
// EPI=0: ihb(bf16) = acc + bias1[col] + bias2[col]
// EPI=1: pre = acc + ihb; hn = d*hb_prev + (1-d)*tanh(pre); hb_next = bf16(hn)
//        if writeOut: out_f32 = hn
template <int EPI>
__global__ __launch_bounds__(512, 2) void gemm_nt(
    const bf16_t* __restrict__ A, const bf16_t* __restrict__ Bw, int M, int N,
    int K, const float* __restrict__ bias1, const float* __restrict__ bias2,
    bf16_t* __restrict__ out_ihb, const bf16_t* __restrict__ ihb,
    const float* __restrict__ decay, const bf16_t* __restrict__ hb_prev,
    bf16_t* __restrict__ hb_next, float* __restrict__ out_f32, int writeOut) {
  extern __shared__ char smem[];  // 131072 B: 2 x 48 KB K-loop, 128 KB epi

  const int tid = threadIdx.x;
  const int lane = tid & 63;
  const int wave = tid >> 6;    // 0..7
  const int waveM = wave >> 1;  // 0..3  (64-row band of 256)
  const int waveN = wave & 1;   // 0..1  (64-col half of 128)

  // XCD swizzle (FETCH ~= compulsory with this mapping; keep)
  const int lin = blockIdx.y * gridDim.x + blockIdx.x;  // 0..255
  const int xcd = lin & 7;
  const int slot = lin >> 3;                    // 0..31
  const int bx = (xcd & 1) * 8 + (slot & 7);    // 0..15 (N/128)
  const int by = (xcd >> 1) * 4 + (slot >> 3);  // 0..15 (M/256)
  const long bRow = (long)by * 256;
  const long bCol = (long)bx * 128;

  // staging: wave stages A row-groups {2w,2w+1} and B row-group w;
  // lane -> row = lane&15, k = (lane>>4)*8 within a 32-wide k-slice
  const int laneRow = lane & 15;
  const int laneK = (lane >> 4) << 3;
  const bf16_t* aG0 = A + (bRow + (wave * 2 + 0) * 16 + laneRow) * (long)K + laneK;
  const bf16_t* aG1 = A + (bRow + (wave * 2 + 1) * 16 + laneRow) * (long)K + laneK;
  const bf16_t* bG = Bw + (bCol + wave * 16 + laneRow) * (long)K + laneK;

  f32x4 acc[4][4] = {};

  // stage one 32-wide k-slice (half-tile): 3 loads/wave
  auto stage_h = [&](int buf, int k0, int ks) {
    bf16_t* base = (bf16_t*)(smem + buf * 49152);
    const int ko = k0 + ks * 32;
    async16(aG0 + ko, base + (wave * 2 + 0) * 1024 + ks * 512);
    async16(aG1 + ko, base + (wave * 2 + 1) * 1024 + ks * 512);
    async16(bG + ko, base + 16384 + wave * 1024 + ks * 512);
  };

  // one phase of compute: 8 ds_read_b128 + 16 MFMA on k-slice ks of buf
  auto phase_compute = [&](int buf, int ks) {
    const bf16_t* Ab = (const bf16_t*)(smem + buf * 49152);
    const bf16_t* Bb = Ab + 16384;
    bf16x8 aF[4], bF[4];
#pragma unroll
    for (int t = 0; t < 4; ++t)
      aF[t] = *(const bf16x8*)&Ab[(waveM * 4 + t) * 1024 + ks * 512 + lane * 8];
#pragma unroll
    for (int u = 0; u < 4; ++u)
      bF[u] = *(const bf16x8*)&Bb[(waveN * 4 + u) * 1024 + ks * 512 + lane * 8];
    __builtin_amdgcn_s_setprio(1);
#pragma unroll
    for (int t = 0; t < 4; ++t)
#pragma unroll
      for (int u = 0; u < 4; ++u)
        acc[t][u] = __builtin_amdgcn_mfma_f32_16x16x32_bf16(aF[t], bF[u],
                                                            acc[t][u], 0, 0, 0);
    __builtin_amdgcn_s_setprio(0);
  };

  const int NT = K >> 6;  // 16 or 32 K-tiles; tile t lives in buf t&1

  // prologue: 3 half-tiles in flight (9 loads/wave)
  stage_h(0, 0, 0);
  stage_h(0, 0, 1);
  stage_h(1, 64, 0);
  asm volatile("s_waitcnt vmcnt(6)" ::: "memory");  // tile0.ks0 landed
  __builtin_amdgcn_s_barrier();
  __builtin_amdgcn_sched_barrier(0);

  int cur = 0;
  for (int t = 0; t < NT - 2; ++t) {
    const int k0 = t * 64;
    // phase A: compute (t,ks0); stage (t+1).ks1 into buf cur^1
    stage_h(cur ^ 1, k0 + 64, 1);
    phase_compute(cur, 0);
    asm volatile("s_waitcnt vmcnt(6)" ::: "memory");  // (t).ks1 landed
    __builtin_amdgcn_s_barrier();
    __builtin_amdgcn_sched_barrier(0);
    // phase B: compute (t,ks1); stage (t+2).ks0 into buf cur (readers done)
    stage_h(cur, k0 + 128, 0);
    phase_compute(cur, 1);
    asm volatile("s_waitcnt vmcnt(6)" ::: "memory");  // (t+1).ks0 landed
    __builtin_amdgcn_s_barrier();
    __builtin_amdgcn_sched_barrier(0);
    cur ^= 1;
  }
  // tail tile NT-2 (buf cur): in flight = {(NT-2).ks1, (NT-1).ks0}
  {
    const int k0 = (NT - 2) * 64;
    stage_h(cur ^ 1, k0 + 64, 1);  // (NT-1).ks1 -> 9 in flight
    phase_compute(cur, 0);
    asm volatile("s_waitcnt vmcnt(6)" ::: "memory");  // (NT-2).ks1 landed
    __builtin_amdgcn_s_barrier();
    __builtin_amdgcn_sched_barrier(0);
    phase_compute(cur, 1);
    asm volatile("s_waitcnt vmcnt(3)" ::: "memory");  // (NT-1).ks0 landed
    __builtin_amdgcn_s_barrier();
    __builtin_amdgcn_sched_barrier(0);
    cur ^= 1;
  }
  // tail tile NT-1 (buf cur)
  {
    phase_compute(cur, 0);
    asm volatile("s_waitcnt vmcnt(0)" ::: "memory");  // (NT-1).ks1 landed
    __builtin_amdgcn_s_barrier();
    __builtin_amdgcn_sched_barrier(0);
    phase_compute(cur, 1);
    asm volatile("s_waitcnt lgkmcnt(0)" ::: "memory");
    __builtin_amdgcn_s_barrier();  // all LDS reads done -> Ep reuse safe
    __builtin_amdgcn_sched_barrier(0);
  }

  // ---- epilogue: LDS transpose (swizzled) then coalesced global I/O ----
  // C/D layout: col = lane&15, row = (lane>>4)*4 + reg   [measured m89/m91]
  float* Ep = (float*)smem;  // 256x128 f32 = 128 KB
  const int eRow = (lane >> 4) << 2;
  const int eCol = lane & 15;
#pragma unroll
  for (int t = 0; t < 4; ++t)
#pragma unroll
    for (int u = 0; u < 4; ++u)
#pragma unroll
      for (int r = 0; r < 4; ++r) {
        const int rowL = waveM * 64 + t * 16 + eRow + r;
        const int colL = waveN * 64 + u * 16 + eCol;
        // swizzle: phys = row*128 + ((col + 4*row) & 127)  (2-way max)
        Ep[rowL * 128 + ((colL + 4 * rowL) & 127)] = acc[t][u][r];
      }
  asm volatile("s_waitcnt lgkmcnt(0)" ::: "memory");
  __builtin_amdgcn_s_barrier();
  __builtin_amdgcn_sched_barrier(0);

  // readers: row = p*64 + tid>>3, 16 consecutive cols at (tid&7)*16
  const int rdRow = tid >> 3;
  const int col0 = (tid & 7) * 16;
#pragma unroll
  for (int p = 0; p < 4; ++p) {
    const int row = p * 64 + rdRow;
    float v[16];
#pragma unroll
    for (int c = 0; c < 4; ++c)
      *(f32x4*)&v[c * 4] =
          *(const f32x4*)&Ep[row * 128 + ((col0 + 4 * c + 4 * row) & 127)];
    const long g = (bRow + row) * (long)N + bCol + col0;

    if (EPI == 0) {
      f32x4 b1[4], b2[4];
#pragma unroll
      for (int c = 0; c < 4; ++c) {
        b1[c] = *(const f32x4*)&bias1[bCol + col0 + c * 4];
        b2[c] = *(const f32x4*)&bias2[bCol + col0 + c * 4];
      }
      bf16x8 o0, o1;
#pragma unroll
      for (int e = 0; e < 8; ++e)
        o0[e] = (bf16_t)(v[e] + b1[e >> 2][e & 3] + b2[e >> 2][e & 3]);
#pragma unroll
      for (int e = 0; e < 8; ++e)
        o1[e] = (bf16_t)(v[8 + e] + b1[2 + (e >> 2)][e & 3] +
                         b2[2 + (e >> 2)][e & 3]);
      *(bf16x8*)&out_ihb[g] = o0;  // 16B/lane, lanes consecutive
      *(bf16x8*)&out_ihb[g + 8] = o1;
    } else {
      const bf16x8 ih0 = *(const bf16x8*)&ihb[g];
      const bf16x8 ih1 = *(const bf16x8*)&ihb[g + 8];
      const bf16x8 hp0 = *(const bf16x8*)&hb_prev[g];
      const bf16x8 hp1 = *(const bf16x8*)&hb_prev[g + 8];
      f32x4 dc[4];
#pragma unroll
      for (int c = 0; c < 4; ++c)
        dc[c] = *(const f32x4*)&decay[bCol + col0 + c * 4];
      float hn[16];
      bf16x8 o0, o1;
#pragma unroll
      for (int e = 0; e < 8; ++e) {
        const float d = dc[e >> 2][e & 3];
        const float th = tanhf(v[e] + (float)ih0[e]);
        hn[e] = d * (float)hp0[e] + (1.0f - d) * th;
        o0[e] = (bf16_t)hn[e];
      }
#pragma unroll
      for (int e = 0; e < 8; ++e) {
        const float d = dc[2 + (e >> 2)][e & 3];
        const float th = tanhf(v[8 + e] + (float)ih1[e]);
        hn[8 + e] = d * (float)hp1[e] + (1.0f - d) * th;
        o1[e] = (bf16_t)hn[8 + e];
      }
      *(bf16x8*)&hb_next[g] = o0;
      *(bf16x8*)&hb_next[g + 8] = o1;
      if (writeOut) {
#pragma unroll
        for (int c = 0; c < 4; ++c)
          *(f32x4*)&out_f32[g + c * 4] = *(const f32x4*)&hn[c * 4];
      }
    }
  }
}

extern "C" void kernel_launch(void* const* d_in, const int* in_sizes, int n_in,
                              void* d_out, int out_size, void* d_ws,
                              size_t ws_size, hipStream_t stream) {
  const float* x = (const float*)d_in[0];
  const float* h0 = (const float*)d_in[1];
  const float* W_ih = (const float*)d_in[2];
  const float* b_ih = (const float*)d_in[3];
  const float* W_hh = (const float*)d_in[4];
  const float* b_hh = (const float*)d_in[5];
  const float* tau = (const float*)d_in[6];
  float* hout = (float*)d_out;

  const int B = 4096, I = 1024, H = 2048;

  char* ws = (char*)d_ws;
  bf16_t* ihb = (bf16_t*)ws; ws += (size_t)B * H * 2;   // 16 MB
  bf16_t* hb0 = (bf16_t*)ws; ws += (size_t)B * H * 2;   // 16 MB
  bf16_t* hb1 = (bf16_t*)ws; ws += (size_t)B * H * 2;   // 16 MB
  bf16_t* xb = (bf16_t*)ws;  ws += (size_t)B * I * 2;   // 8 MB
  bf16_t* wihb = (bf16_t*)ws; ws += (size_t)H * I * 2;  // 4 MB
  bf16_t* whhb = (bf16_t*)ws; ws += (size_t)H * H * 2;  // 8 MB
  float* decay = (float*)ws; ws += (size_t)H * 4;       // 8 KB

  const int LDS_BYTES = 131072;  // 2 x 48 KB K-loop buffers; 128 KB epilogue
  (void)hipFuncSetAttribute(reinterpret_cast<const void*>(&gemm_nt<0>),
                            hipFuncAttributeMaxDynamicSharedMemorySize,
                            LDS_BYTES);
  (void)hipFuncSetAttribute(reinterpret_cast<const void*>(&gemm_nt<1>),
                            hipFuncAttributeMaxDynamicSharedMemorySize,
                            LDS_BYTES);

  cvt_f32_to_bf16<<<(B * I / 4 + 255) / 256, 256, 0, stream>>>(x, xb, B * I / 4);
  cvt_f32_to_bf16<<<(H * I / 4 + 255) / 256, 256, 0, stream>>>(W_ih, wihb, H * I / 4);
  cvt_f32_to_bf16<<<(H * H / 4 + 255) / 256, 256, 0, stream>>>(W_hh, whhb, H * H / 4);
  cvt_f32_to_bf16<<<(B * H / 4 + 255) / 256, 256, 0, stream>>>(h0, hb0, B * H / 4);
  make_decay<<<(H + 255) / 256, 256, 0, stream>>>(tau, decay, H);

  dim3 grid(H / 128, B / 256);  // (16, 16) = 256 blocks = 1/CU
  // ihb = x @ W_ih^T + b_ih + b_hh   (fold both biases once, store bf16)
  gemm_nt<0><<<grid, 512, LDS_BYTES, stream>>>(
      xb, wihb, B, H, I, b_ih, b_hh, ihb, nullptr, nullptr, nullptr, nullptr,
      nullptr, 0);

  bf16_t* hb[2] = {hb0, hb1};
  for (int s = 0; s < NUM_STEPS; ++s) {
    gemm_nt<1><<<grid, 512, LDS_BYTES, stream>>>(
        hb[s & 1], whhb, B, H, H, nullptr, nullptr, nullptr, ihb, decay,
        hb[s & 1], hb[(s + 1) & 1], hout, (s == NUM_STEPS - 1) ? 1 : 0);
  }
}

// Round 4
// 729.095 us; speedup vs baseline: 1.0104x; 1.0104x over previous
//
#include <hip/hip_runtime.h>
#include <hip/hip_bf16.h>

#define NUM_STEPS 10
#define DT 0.1f

typedef __bf16 bf16_t;
typedef __bf16 bf16x8 __attribute__((ext_vector_type(8)));
typedef __bf16 bf16x4 __attribute__((ext_vector_type(4)));
typedef float f32x4 __attribute__((ext_vector_type(4)));

// async global->LDS, 16B per lane; LDS dst is wave-uniform base + lane*16
__device__ __forceinline__ void async16(const bf16_t* g, bf16_t* l) {
  __builtin_amdgcn_global_load_lds(
      (const __attribute__((address_space(1))) void*)g,
      (__attribute__((address_space(3))) void*)l, 16, 0, 0);
}

__global__ void cvt_f32_to_bf16(const float* __restrict__ in,
                                bf16_t* __restrict__ out, int n4) {
  int i = blockIdx.x * blockDim.x + threadIdx.x;
  if (i < n4) {
    float4 v = ((const float4*)in)[i];
    bf16x4 o = {(bf16_t)v.x, (bf16_t)v.y, (bf16_t)v.z, (bf16_t)v.w};
    ((bf16x4*)out)[i] = o;
  }
}

// one-shot: decay[h] = exp(-dt/tau[h])
__global__ void make_decay(const float* __restrict__ tau,
                           float* __restrict__ decay, int n) {
  int i = blockIdx.x * blockDim.x + threadIdx.x;
  if (i < n) decay[i] = __expf(-DT / tau[i]);
}

// C[M,N] = A[M,K] * B[N,K]^T   (NT, both row-major, K contiguous)
// Round 4: same tile (BM=256 BN=128 BK=64, 3x48KB buffers, counted vmcnt,
// verified addressing/epilogue) but 16 WAVES (1024 thr) = 4 waves/SIMD.
// Rounds 2-3 showed identical perf for burst vs phase schedules at 8 waves:
// with 2 waves/SIMD in barrier lockstep the LDS and MFMA pipes serialize
// (sum not max) and latencies are exposed. 16 waves restores cross-wave
// pipe overlap (m114). Per-wave output 64x32: aF4+bF2 ds_reads, 8 MFMA per
// k-slice; staging 3 loads/wave/tile (A group w x2 kslices, one B slice).
// LDS-read grows 128->192 KB/tile (accepted; new expected wall ~50% MfmaUtil).
// EPI=0: ihb(bf16) = acc + bias1[col] + bias2[col]
// EPI=1: pre = acc + ihb; hn = d*hb_prev + (1-d)*tanh(pre); hb_next = bf16(hn)
//        if writeOut: out_f32 = hn
template <int EPI>
__global__ __launch_bounds__(1024, 4) void gemm_nt(
    const bf16_t* __restrict__ A, const bf16_t* __restrict__ Bw, int M, int N,
    int K, const float* __restrict__ bias1, const float* __restrict__ bias2,
    bf16_t* __restrict__ out_ihb, const bf16_t* __restrict__ ihb,
    const float* __restrict__ decay, const bf16_t* __restrict__ hb_prev,
    bf16_t* __restrict__ hb_next, float* __restrict__ out_f32, int writeOut) {
  extern __shared__ char smem[];  // 147456 B: 3 x 48 KB K-loop; 128 KB epi

  const int tid = threadIdx.x;
  const int lane = tid & 63;
  const int wave = tid >> 6;    // 0..15
  const int waveM = wave >> 2;  // 0..3  (64-row band of 256)
  const int waveN = wave & 3;   // 0..3  (32-col band of 128)

  // XCD swizzle (verified mapping; FETCH ~= compulsory)
  const int lin = blockIdx.y * gridDim.x + blockIdx.x;  // 0..255
  const int xcd = lin & 7;
  const int slot = lin >> 3;                    // 0..31
  const int bx = (xcd & 1) * 8 + (slot & 7);    // 0..15 (N/128)
  const int by = (xcd >> 1) * 4 + (slot >> 3);  // 0..15 (M/256)
  const long bRow = (long)by * 256;
  const long bCol = (long)bx * 128;

  // staging (16 waves, 3 loads/wave/tile):
  //   A: 16 row-groups of 16; wave w stages group w, kslices 0 and 1
  //   B: 8 row-groups; wave w stages group w&7, kslice w>>3
  // lane -> row = lane&15, k = (lane>>4)*8 within a 32-wide k-slice
  const int laneRow = lane & 15;
  const int laneK = (lane >> 4) << 3;
  const bf16_t* aG = A + (bRow + wave * 16 + laneRow) * (long)K + laneK;
  const bf16_t* bG = Bw + (bCol + (wave & 7) * 16 + laneRow) * (long)K +
                     laneK + (wave >> 3) * 32;
  const int aOff = wave * 1024;                            // A group w base
  const int bOff = 16384 + (wave & 7) * 1024 + (wave >> 3) * 512;

  f32x4 acc[4][2] = {};

  auto stage = [&](int buf, int k0) {
    bf16_t* base = (bf16_t*)(smem + buf * 49152);
    async16(aG + k0, base + aOff);          // A group w, ks0
    async16(aG + k0 + 32, base + aOff + 512);  // A group w, ks1
    async16(bG + k0, base + bOff);          // B group w&7, ks w>>3
  };

  // one k-slice: 6 ds_read_b128 + 8 MFMA
  auto compute = [&](int buf, int ks) {
    const bf16_t* Ab = (const bf16_t*)(smem + buf * 49152);
    const bf16_t* Bb = Ab + 16384;
    bf16x8 aF[4], bF[2];
#pragma unroll
    for (int t = 0; t < 4; ++t)
      aF[t] = *(const bf16x8*)&Ab[(waveM * 4 + t) * 1024 + ks * 512 + lane * 8];
#pragma unroll
    for (int u = 0; u < 2; ++u)
      bF[u] = *(const bf16x8*)&Bb[(waveN * 2 + u) * 1024 + ks * 512 + lane * 8];
    __builtin_amdgcn_s_setprio(1);
#pragma unroll
    for (int t = 0; t < 4; ++t)
#pragma unroll
      for (int u = 0; u < 2; ++u)
        acc[t][u] = __builtin_amdgcn_mfma_f32_16x16x32_bf16(aF[t], bF[u],
                                                            acc[t][u], 0, 0, 0);
    __builtin_amdgcn_s_setprio(0);
  };

  const int NT = K >> 6;  // 16 or 32 K-tiles; tile t lives in buf t%3

  // prologue: tiles 0,1 in flight (6 loads/wave)
  stage(0, 0);
  stage(1, 64);
  asm volatile("s_waitcnt vmcnt(3)" ::: "memory");  // tile 0 landed
  __builtin_amdgcn_s_barrier();
  __builtin_amdgcn_sched_barrier(0);

  int cb = 0, sb = 2;
  for (int t = 0; t < NT - 2; ++t) {
    stage(sb, (t + 2) * 64);            // issue 3 loads for tile t+2
    __builtin_amdgcn_sched_barrier(0);  // keep issue ahead of compute
    compute(cb, 0);
    compute(cb, 1);
    // outstanding: tile t+1 (3) + tile t+2 (3); ensure t+1 landed
    asm volatile("s_waitcnt vmcnt(3)" ::: "memory");
    __builtin_amdgcn_s_barrier();
    __builtin_amdgcn_sched_barrier(0);
    cb = cb + 1; if (cb == 3) cb = 0;
    sb = sb + 1; if (sb == 3) sb = 0;
  }
  // tile NT-2: nothing left to stage
  compute(cb, 0);
  compute(cb, 1);
  asm volatile("s_waitcnt vmcnt(0)" ::: "memory");  // tile NT-1 landed
  __builtin_amdgcn_s_barrier();
  __builtin_amdgcn_sched_barrier(0);
  cb = cb + 1; if (cb == 3) cb = 0;
  // tile NT-1
  compute(cb, 0);
  compute(cb, 1);
  asm volatile("s_waitcnt lgkmcnt(0)" ::: "memory");
  __builtin_amdgcn_s_barrier();  // all LDS reads done -> Ep reuse safe
  __builtin_amdgcn_sched_barrier(0);

  // ---- epilogue: LDS transpose (swizzled) then coalesced global I/O ----
  // C/D layout: col = lane&15, row = (lane>>4)*4 + reg   [measured m89/m91]
  float* Ep = (float*)smem;  // 256x128 f32 = 128 KB
  const int eRow = (lane >> 4) << 2;
  const int eCol = lane & 15;
#pragma unroll
  for (int t = 0; t < 4; ++t)
#pragma unroll
    for (int u = 0; u < 2; ++u)
#pragma unroll
      for (int r = 0; r < 4; ++r) {
        const int rowL = waveM * 64 + t * 16 + eRow + r;
        const int colL = waveN * 32 + u * 16 + eCol;
        // swizzle: phys = row*128 + ((col + 4*row) & 127)  (2-way max)
        Ep[rowL * 128 + ((colL + 4 * rowL) & 127)] = acc[t][u][r];
      }
  asm volatile("s_waitcnt lgkmcnt(0)" ::: "memory");
  __builtin_amdgcn_s_barrier();
  __builtin_amdgcn_sched_barrier(0);

  // readers: 1024 thr: row = p*128 + tid>>3, 16 consecutive cols at (tid&7)*16
  const int rdRow = tid >> 3;
  const int col0 = (tid & 7) * 16;
#pragma unroll
  for (int p = 0; p < 2; ++p) {
    const int row = p * 128 + rdRow;
    float v[16];
#pragma unroll
    for (int c = 0; c < 4; ++c)
      *(f32x4*)&v[c * 4] =
          *(const f32x4*)&Ep[row * 128 + ((col0 + 4 * c + 4 * row) & 127)];
    const long g = (bRow + row) * (long)N + bCol + col0;

    if (EPI == 0) {
      f32x4 b1[4], b2[4];
#pragma unroll
      for (int c = 0; c < 4; ++c) {
        b1[c] = *(const f32x4*)&bias1[bCol + col0 + c * 4];
        b2[c] = *(const f32x4*)&bias2[bCol + col0 + c * 4];
      }
      bf16x8 o0, o1;
#pragma unroll
      for (int e = 0; e < 8; ++e)
        o0[e] = (bf16_t)(v[e] + b1[e >> 2][e & 3] + b2[e >> 2][e & 3]);
#pragma unroll
      for (int e = 0; e < 8; ++e)
        o1[e] = (bf16_t)(v[8 + e] + b1[2 + (e >> 2)][e & 3] +
                         b2[2 + (e >> 2)][e & 3]);
      *(bf16x8*)&out_ihb[g] = o0;  // 16B/lane, lanes consecutive
      *(bf16x8*)&out_ihb[g + 8] = o1;
    } else {
      const bf16x8 ih0 = *(const bf16x8*)&ihb[g];
      const bf16x8 ih1 = *(const bf16x8*)&ihb[g + 8];
      const bf16x8 hp0 = *(const bf16x8*)&hb_prev[g];
      const bf16x8 hp1 = *(const bf16x8*)&hb_prev[g + 8];
      f32x4 dc[4];
#pragma unroll
      for (int c = 0; c < 4; ++c)
        dc[c] = *(const f32x4*)&decay[bCol + col0 + c * 4];
      float hn[16];
      bf16x8 o0, o1;
#pragma unroll
      for (int e = 0; e < 8; ++e) {
        const float d = dc[e >> 2][e & 3];
        const float th = tanhf(v[e] + (float)ih0[e]);
        hn[e] = d * (float)hp0[e] + (1.0f - d) * th;
        o0[e] = (bf16_t)hn[e];
      }
#pragma unroll
      for (int e = 0; e < 8; ++e) {
        const float d = dc[2 + (e >> 2)][e & 3];
        const float th = tanhf(v[8 + e] + (float)ih1[e]);
        hn[8 + e] = d * (float)hp1[e] + (1.0f - d) * th;
        o1[e] = (bf16_t)hn[8 + e];
      }
      *(bf16x8*)&hb_next[g] = o0;
      *(bf16x8*)&hb_next[g + 8] = o1;
      if (writeOut) {
#pragma unroll
        for (int c = 0; c < 4; ++c)
          *(f32x4*)&out_f32[g + c * 4] = *(const f32x4*)&hn[c * 4];
      }
    }
  }
}

extern "C" void kernel_launch(void* const* d_in, const int* in_sizes, int n_in,
                              void* d_out, int out_size, void* d_ws,
                              size_t ws_size, hipStream_t stream) {
  const float* x = (const float*)d_in[0];
  const float* h0 = (const float*)d_in[1];
  const float* W_ih = (const float*)d_in[2];
  const float* b_ih = (const float*)d_in[3];
  const float* W_hh = (const float*)d_in[4];
  const float* b_hh = (const float*)d_in[5];
  const float* tau = (const float*)d_in[6];
  float* hout = (float*)d_out;

  const int B = 4096, I = 1024, H = 2048;

  char* ws = (char*)d_ws;
  bf16_t* ihb = (bf16_t*)ws; ws += (size_t)B * H * 2;   // 16 MB
  bf16_t* hb0 = (bf16_t*)ws; ws += (size_t)B * H * 2;   // 16 MB
  bf16_t* hb1 = (bf16_t*)ws; ws += (size_t)B * H * 2;   // 16 MB
  bf16_t* xb = (bf16_t*)ws;  ws += (size_t)B * I * 2;   // 8 MB
  bf16_t* wihb = (bf16_t*)ws; ws += (size_t)H * I * 2;  // 4 MB
  bf16_t* whhb = (bf16_t*)ws; ws += (size_t)H * H * 2;  // 8 MB
  float* decay = (float*)ws; ws += (size_t)H * 4;       // 8 KB

  const int LDS_BYTES = 147456;  // 3 x 48 KB K-loop; 128 KB epilogue reuse
  (void)hipFuncSetAttribute(reinterpret_cast<const void*>(&gemm_nt<0>),
                            hipFuncAttributeMaxDynamicSharedMemorySize,
                            LDS_BYTES);
  (void)hipFuncSetAttribute(reinterpret_cast<const void*>(&gemm_nt<1>),
                            hipFuncAttributeMaxDynamicSharedMemorySize,
                            LDS_BYTES);

  cvt_f32_to_bf16<<<(B * I / 4 + 255) / 256, 256, 0, stream>>>(x, xb, B * I / 4);
  cvt_f32_to_bf16<<<(H * I / 4 + 255) / 256, 256, 0, stream>>>(W_ih, wihb, H * I / 4);
  cvt_f32_to_bf16<<<(H * H / 4 + 255) / 256, 256, 0, stream>>>(W_hh, whhb, H * H / 4);
  cvt_f32_to_bf16<<<(B * H / 4 + 255) / 256, 256, 0, stream>>>(h0, hb0, B * H / 4);
  make_decay<<<(H + 255) / 256, 256, 0, stream>>>(tau, decay, H);

  dim3 grid(H / 128, B / 256);  // (16, 16) = 256 blocks = 1/CU
  // ihb = x @ W_ih^T + b_ih + b_hh   (fold both biases once, store bf16)
  gemm_nt<0><<<grid, 1024, LDS_BYTES, stream>>>(
      xb, wihb, B, H, I, b_ih, b_hh, ihb, nullptr, nullptr, nullptr, nullptr,
      nullptr, 0);

  bf16_t* hb[2] = {hb0, hb1};
  for (int s = 0; s < NUM_STEPS; ++s) {
    gemm_nt<1><<<grid, 1024, LDS_BYTES, stream>>>(
        hb[s & 1], whhb, B, H, H, nullptr, nullptr, nullptr, ihb, decay,
        hb[s & 1], hb[(s + 1) & 1], hout, (s == NUM_STEPS - 1) ? 1 : 0);
  }
}